// Round 3
// baseline (363.194 us; speedup 1.0000x reference)
//
#include <hip/hip_runtime.h>

#define BB   4
#define CC   256
#define HH   128
#define WW   128
#define PAD  4
#define KOUT 81

#define TH    8       // output rows per block (one per wave)
#define SW    16      // output cols per block (one MFMA M-tile)
#define KC    32      // channels per chunk (one MFMA K step)
#define NCHUNK (CC / KC)
#define NG    3       // dy groups: g handles dy = 3g .. 3g+2
#define BROWS 11      // i2 rows staged per group: wave(0..7)+dd(0..2) -> 11 rows
#define BPTS  (BROWS * 24)        // 264 B-points
#define APTS  (TH * 16)           // 128 A-points
#define AK    40      // padded K-stride per LDS point (80 B, 16B-aligned)

typedef _Float16 half8 __attribute__((ext_vector_type(8)));
typedef float    f32x4 __attribute__((ext_vector_type(4)));

__global__ __launch_bounds__(512, 6)
void corr_mfma3(const float* __restrict__ i1,
                const float* __restrict__ i2,
                float* __restrict__ out)
{
    // B first (264 pts), then A (128 pts). q>=24 frag reads overflow into A
    // region -> finite garbage feeding dx>8 outputs which are never stored.
    __shared__ _Float16 sh[(BPTS + APTS) * AK];   // 31,360 B

    const int t    = threadIdx.x;
    const int wave = t >> 6;
    const int lane = t & 63;
    const int l15  = lane & 15;
    const int quad = lane >> 4;

    const int z  = blockIdx.z;          // b * NG + g
    const int b  = z / NG;
    const int g  = z - b * NG;          // dy group 0..2
    const int h0 = blockIdx.y * TH;
    const int w0 = blockIdx.x * SW;

    const size_t strideC = (size_t)HH * WW;
    const float* i1b = i1 + (size_t)b * CC * strideC;
    const float* i2b = i2 + (size_t)b * CC * strideC;

    // ---- staging role: one (point) per thread, thread owns all 32 channels
    //      of the current chunk (contiguous K-run in LDS).
    const bool stager = (t < BPTS + APTS);
    bool valid = false;
    const float* gptr = i1b;            // dummy init
    _Float16* ldst = sh;
    if (t < BPTS) {
        const int sq  = t % 24;
        const int sr  = t / 24;
        const int col = w0 - PAD + sq;
        const int row = h0 - PAD + 3 * g + sr;
        valid = (col >= 0) && (col < WW) && (row >= 0) && (row < HH);
        gptr  = i2b + (size_t)(valid ? row : 0) * WW + (valid ? col : 0);
        ldst  = &sh[(sr * 24 + sq) * AK];
    } else if (stager) {
        const int i  = t - BPTS;
        const int sm = i & 15;
        const int sr = i >> 4;
        valid = true;
        gptr  = i1b + (size_t)(h0 + sr) * WW + (w0 + sm);
        ldst  = &sh[(BPTS + sr * 16 + sm) * AK];
    }

    f32x4 acc[NG][2];
#pragma unroll
    for (int dd = 0; dd < NG; ++dd) {
        acc[dd][0] = (f32x4){0.f, 0.f, 0.f, 0.f};
        acc[dd][1] = (f32x4){0.f, 0.f, 0.f, 0.f};
    }

#pragma unroll 1
    for (int ch = 0; ch < NCHUNK; ++ch) {
        // ---- stage chunk ch ----
        if (ch > 0) __syncthreads();    // waves done reading chunk ch-1
        if (stager) {
            const float* gp = gptr + (size_t)ch * KC * strideC;
            float v[KC];
#pragma unroll
            for (int j = 0; j < KC; ++j)
                v[j] = valid ? gp[(size_t)j * strideC] : 0.f;
#pragma unroll
            for (int u = 0; u < 4; ++u) {
                half8 hv;
#pragma unroll
                for (int k = 0; k < 8; ++k) hv[k] = (_Float16)v[8 * u + k];
                *(half8*)&ldst[8 * u] = hv;
            }
        }
        __syncthreads();

        // ---- compute: one output row per wave, 3 dy x 2 N-tiles ----
        const half8 a = *(const half8*)&sh[(BPTS + wave * 16 + l15) * AK + quad * 8];
#pragma unroll
        for (int dd = 0; dd < NG; ++dd) {
            const int r = wave + dd;    // local B row (global dy = 3g+dd)
            const half8 b0 = *(const half8*)&sh[(r * 24 + l15) * AK + quad * 8];
            acc[dd][0] = __builtin_amdgcn_mfma_f32_16x16x32_f16(a, b0, acc[dd][0], 0, 0, 0);
            const half8 b1 = *(const half8*)&sh[(r * 24 + 16 + l15) * AK + quad * 8];
            acc[dd][1] = __builtin_amdgcn_mfma_f32_16x16x32_f16(a, b1, acc[dd][1], 0, 0, 0);
        }
    }

    // ---- epilogue: D[p][q], p = quad*4+reg, q = l15 + 16*tt, dx = q - p ----
    const int h = h0 + wave;
#pragma unroll
    for (int dd = 0; dd < NG; ++dd) {
        const int dy = 3 * g + dd;
#pragma unroll
        for (int tt = 0; tt < 2; ++tt) {
#pragma unroll
            for (int reg = 0; reg < 4; ++reg) {
                const int p  = quad * 4 + reg;
                const int dx = l15 + 16 * tt - p;
                if (dx >= 0 && dx <= 8) {
                    out[(((size_t)b * KOUT + (dy * 9 + dx)) * HH + h) * WW + (w0 + p)] =
                        acc[dd][tt][reg];
                }
            }
        }
    }
}

extern "C" void kernel_launch(void* const* d_in, const int* in_sizes, int n_in,
                              void* d_out, int out_size, void* d_ws, size_t ws_size,
                              hipStream_t stream)
{
    (void)in_sizes; (void)n_in; (void)d_ws; (void)ws_size; (void)out_size;
    const float* i1 = (const float*)d_in[0];
    const float* i2 = (const float*)d_in[1];
    float* out = (float*)d_out;

    dim3 grid(WW / SW, HH / TH, BB * NG);   // (8, 16, 12) = 1536 blocks, 6/CU
    dim3 block(512);
    corr_mfma3<<<grid, block, 0, stream>>>(i1, i2, out);
}

// Round 4
// 190.288 us; speedup vs baseline: 1.9087x; 1.9087x over previous
//
#include <hip/hip_runtime.h>

#define BB   4
#define CC   256
#define HH   128
#define WW   128
#define PAD  4
#define KOUT 81

#define TH   8        // output rows per block (one per wave)
#define SW   16       // output cols per block (one MFMA M-tile)
#define KC   32       // channels per chunk (one MFMA K step)
#define NCHUNK (CC / KC)
#define AK   40       // padded K-stride per LDS point (80 B, 16B-aligned)

typedef _Float16 half8 __attribute__((ext_vector_type(8)));
typedef float    f32x4 __attribute__((ext_vector_type(4)));

__global__ __launch_bounds__(512, 3)
void corr_mfma4(const float* __restrict__ i1,
                const float* __restrict__ i2,
                float* __restrict__ out)
{
    // B: 384 pts (16 rows x 24 q), then A: 128 pts (8 rows x 16 m).
    // q>=24 fragment reads see garbage feeding dx>8 outputs (never stored).
    __shared__ _Float16 Bld[384 * AK];   // 30720 B
    __shared__ _Float16 Ald[128 * AK];   // 10240 B

    const int t    = threadIdx.x;
    const int wave = t >> 6;
    const int lane = t & 63;
    const int l15  = lane & 15;
    const int quad = lane >> 4;

    const int b  = blockIdx.z;
    const int h0 = blockIdx.y * TH;
    const int w0 = blockIdx.x * SW;

    const size_t strideC = (size_t)HH * WW;
    const float* i1b = i1 + (size_t)b * CC * strideC;   // uniform (SGPR) base
    const float* i2b = i2 + (size_t)b * CC * strideC;   // uniform (SGPR) base

    // ---- staging roles: waves 0..5 stage B (one (r,q) point each),
    //      waves 6..7 stage A. Thread owns all KC channels of its point.
    //      Address = uniform channel base (SGPR) + per-thread pixel offset
    //      (single 32-bit VGPR) -> all KC loads issue back-to-back.
    const bool isB = (t < 384);
    bool valid;
    int pix;              // per-thread pixel offset (elements)
    _Float16* ldst;
    if (isB) {
        const int sq  = t % 24;
        const int sr  = t / 24;
        const int col = w0 - PAD + sq;
        const int row = h0 - PAD + sr;
        valid = (col >= 0) && (col < WW) && (row >= 0) && (row < HH);
        pix   = valid ? (row * WW + col) : 0;
        ldst  = &Bld[(sr * 24 + sq) * AK];
    } else {
        const int i  = t - 384;
        const int sm = i & 15;
        const int sr = i >> 4;
        valid = true;
        pix   = (h0 + sr) * WW + (w0 + sm);
        ldst  = &Ald[(sr * 16 + sm) * AK];
    }

    f32x4 acc[9][2];
#pragma unroll
    for (int dy = 0; dy < 9; ++dy) {
        acc[dy][0] = (f32x4){0.f, 0.f, 0.f, 0.f};
        acc[dy][1] = (f32x4){0.f, 0.f, 0.f, 0.f};
    }

    float v[KC];

    // ---- load chunk `ch` into v[] with scalar-base addressing ----
#define LOAD_CHUNK(CH)                                                        \
    do {                                                                      \
        const int c0_ = (CH) * KC;                                            \
        if (isB) {                                                            \
            _Pragma("unroll")                                                 \
            for (int j = 0; j < KC; ++j) {                                    \
                const float* cb = i2b + (size_t)(c0_ + j) * strideC;          \
                float x = cb[pix];                                            \
                v[j] = valid ? x : 0.f;                                       \
            }                                                                 \
        } else {                                                              \
            _Pragma("unroll")                                                 \
            for (int j = 0; j < KC; ++j) {                                    \
                const float* cb = i1b + (size_t)(c0_ + j) * strideC;          \
                v[j] = cb[pix];                                               \
            }                                                                 \
        }                                                                     \
    } while (0)

#define STORE_CHUNK()                                                         \
    do {                                                                      \
        _Pragma("unroll")                                                     \
        for (int u = 0; u < 4; ++u) {                                         \
            half8 hv;                                                         \
            _Pragma("unroll")                                                 \
            for (int k = 0; k < 8; ++k) hv[k] = (_Float16)v[8 * u + k];       \
            *(half8*)&ldst[8 * u] = hv;                                       \
        }                                                                     \
    } while (0)

    // ---- prologue: stage chunk 0 ----
    LOAD_CHUNK(0);
    STORE_CHUNK();
    __syncthreads();

#pragma unroll 1
    for (int ch = 0; ch < NCHUNK; ++ch) {
        // prefetch next chunk's globals into registers (loads stay in flight
        // across the MFMA phase; vmcnt wait happens just before STORE_CHUNK)
        if (ch + 1 < NCHUNK) LOAD_CHUNK(ch + 1);

        // compute current chunk: one output row per wave, 9 dy x 2 N-tiles
        {
            const half8 a = *(const half8*)&Ald[(wave * 16 + l15) * AK + quad * 8];
#pragma unroll
            for (int dy = 0; dy < 9; ++dy) {
                const int r = wave + dy;
                const half8 b0 = *(const half8*)&Bld[(r * 24 + l15) * AK + quad * 8];
                acc[dy][0] = __builtin_amdgcn_mfma_f32_16x16x32_f16(a, b0, acc[dy][0], 0, 0, 0);
                const half8 b1 = *(const half8*)&Bld[(r * 24 + 16 + l15) * AK + quad * 8];
                acc[dy][1] = __builtin_amdgcn_mfma_f32_16x16x32_f16(a, b1, acc[dy][1], 0, 0, 0);
            }
        }

        if (ch + 1 < NCHUNK) {
            __syncthreads();   // all waves done reading LDS for chunk ch
            STORE_CHUNK();
            __syncthreads();   // chunk ch+1 visible
        }
    }

    // ---- epilogue: D[p][q], p = quad*4+reg, q = l15 + 16*tt, dx = q - p ----
    const int h = h0 + wave;
#pragma unroll
    for (int dy = 0; dy < 9; ++dy) {
#pragma unroll
        for (int tt = 0; tt < 2; ++tt) {
#pragma unroll
            for (int reg = 0; reg < 4; ++reg) {
                const int p  = quad * 4 + reg;
                const int dx = l15 + 16 * tt - p;
                if (dx >= 0 && dx <= 8) {
                    out[(((size_t)b * KOUT + (dy * 9 + dx)) * HH + h) * WW + (w0 + p)] =
                        acc[dy][tt][reg];
                }
            }
        }
    }
#undef LOAD_CHUNK
#undef STORE_CHUNK
}

extern "C" void kernel_launch(void* const* d_in, const int* in_sizes, int n_in,
                              void* d_out, int out_size, void* d_ws, size_t ws_size,
                              hipStream_t stream)
{
    (void)in_sizes; (void)n_in; (void)d_ws; (void)ws_size; (void)out_size;
    const float* i1 = (const float*)d_in[0];
    const float* i2 = (const float*)d_in[1];
    float* out = (float*)d_out;

    dim3 grid(WW / SW, HH / TH, BB);   // (8, 16, 4) = 512 blocks
    dim3 block(512);
    corr_mfma4<<<grid, block, 0, stream>>>(i1, i2, out);
}